// Round 5
// baseline (95.363 us; speedup 1.0000x reference)
//
#include <hip/hip_runtime.h>
#include <cstdint>
#include <cstddef>

#define NTOT   22743     // 1083 + 4332 + 17328
#define N1     1083
#define N12    5415
#define BATCH  64
#define KCAND  512
#define NSEG   16        // segments per image
#define SEGLEN 1422      // ceil(NTOT/NSEG)
#define CAPS   384       // per-(b,c,seg) capacity (expected ~114, 3.4x headroom)
#define CAP    4096      // per-(b,c) total candidate capacity in LDS
#define MAXPC  100
#define MAXTOT 100

__device__ __forceinline__ float sigmoidf(float x) { return 1.0f / (1.0f + expf(-x)); }

// ---------------------------------------------------------------- kernel 1
// filter: block = (image b, segment s). Candidates -> LDS lists (wave-
// aggregated LDS atomics) -> PRIVATE global slot with plain stores.
__global__ __launch_bounds__(256) void score_filter_kernel(
    const float* __restrict__ p1, const float* __restrict__ p2,
    const float* __restrict__ p3, uint2* __restrict__ cand,
    uint32_t* __restrict__ counts)
{
  const int blk  = blockIdx.x;
  const int b    = blk >> 4;            // image
  const int s    = blk & 15;            // segment
  const int tid  = threadIdx.x;
  const int lane = tid & 63;

  __shared__ uint2    lst[2][CAPS];
  __shared__ uint32_t lcnt[2];

  if (tid < 2) lcnt[tid] = 0u;
  __syncthreads();

  const int beg = s * SEGLEN;
  int end = beg + SEGLEN; if (end > NTOT) end = NTOT;

  for (int i0 = beg + tid; i0 < beg + SEGLEN; i0 += 256) {
    float s0 = 0.f, s1 = 0.f;
    if (i0 < end) {
      const float* p; int local, per;
      if (i0 < N1)       { p = p1; local = i0;        per = 1083; }
      else if (i0 < N12) { p = p2; local = i0 - N1;   per = 4332; }
      else               { p = p3; local = i0 - N12;  per = 17328; }
      const float* q = p + ((size_t)b * per + local) * 7;
      float q4 = q[4];
      if (q4 > 0.f) {                 // sig(q4)<=0.5 -> product < 0.5 strictly
        float obj = sigmoidf(q4);
        s0 = obj * sigmoidf(q[5]);
        s1 = obj * sigmoidf(q[6]);
      }
    }
    #pragma unroll
    for (int c = 0; c < 2; c++) {
      float sc = (c == 0) ? s0 : s1;
      bool pred = sc > 0.5f;
      unsigned long long m = __ballot(pred ? 1 : 0);
      if (m != 0ull) {
        int leader = (int)__ffsll(m) - 1;
        uint32_t base = 0u;
        if (lane == leader) base = atomicAdd(&lcnt[c], (uint32_t)__popcll(m));
        base = (uint32_t)__shfl((int)base, leader);
        if (pred) {
          uint32_t off = base + (uint32_t)__popcll(m & ((1ull << lane) - 1ull));
          if (off < CAPS) lst[c][off] = make_uint2(__float_as_uint(sc), (uint32_t)i0);
        }
      }
    }
  }
  __syncthreads();

  #pragma unroll
  for (int c = 0; c < 2; c++) {
    uint32_t cnt = lcnt[c]; if (cnt > CAPS) cnt = CAPS;
    uint2* dst = cand + ((size_t)((b * 2 + c) * NSEG + s)) * CAPS;
    for (uint32_t i = tid; i < cnt; i += 256) dst[i] = lst[c][i];
    if (tid == 0) counts[(b * 2 + c) * NSEG + s] = cnt;
  }
}

// box decode for global candidate index i of image b
__device__ void decode_box(const float* __restrict__ p1, const float* __restrict__ p2,
                           const float* __restrict__ p3, const float* __restrict__ anch,
                           int b, int i, float bb[4])
{
  const float* p; int local, g, abase, per;
  if (i < N1)       { p = p1; local = i;       g = 19; abase = 6; per = 1083; }
  else if (i < N12) { p = p2; local = i - N1;  g = 38; abase = 3; per = 4332; }
  else              { p = p3; local = i - N12; g = 76; abase = 0; per = 17328; }
  const float* q = p + ((size_t)b * per + local) * 7;
  int a    = local % 3;
  int cell = local / 3;
  int col  = cell % g;
  int row  = cell / g;
  float aw = anch[(abase + a) * 2 + 0];
  float ah = anch[(abase + a) * 2 + 1];
  float x = (sigmoidf(q[0]) + (float)col) / (float)g;
  float y = (sigmoidf(q[1]) + (float)row) / (float)g;
  float w = expf(q[2]) * aw;
  float h = expf(q[3]) * ah;
  float x1 = x - w * 0.5f;
  float y1 = y - h * 0.5f;
  bb[0] = x1; bb[1] = y1; bb[2] = x1 + w; bb[3] = y1 + h;
}

// ---------------------------------------------------------------- kernel 2
// one block (512 thr) per (image, class): concat segments, radix-select the
// 512th key, collect >= K as packed u64 (key<<32 | ~idx), bitonic-1024 desc
// (exact (score desc, idx asc) order), decode boxes -> global.
__global__ __launch_bounds__(512) void select_sort_kernel(
    const uint2* __restrict__ cand, const uint32_t* __restrict__ counts,
    const float* __restrict__ p1, const float* __restrict__ p2,
    const float* __restrict__ p3, const float* __restrict__ anch,
    float4* __restrict__ boxesS, float* __restrict__ areaS,
    uint32_t* __restrict__ keyS, int* __restrict__ limitG)
{
  const int bc   = blockIdx.x;   // b*2 + c
  const int b    = bc >> 1;
  const int tid  = threadIdx.x;
  const int lane = tid & 63;

  __shared__ uint2 kv[CAP];                 // 32 KB concatenated candidates
  __shared__ unsigned long long sw[1024];   //  8 KB packed sort buffer
  __shared__ uint32_t hist[256];
  __shared__ uint32_t pcnt[17];
  __shared__ uint32_t svar[8];

  // ---- parallel prefix of the 16 segment counts
  if (tid <= 16) {
    uint32_t off = 0;
    for (int t = 0; t < tid; ++t) {
      uint32_t cs = counts[bc * NSEG + t]; if (cs > CAPS) cs = CAPS;
      off += cs;
    }
    pcnt[tid] = off;
  }
  if (tid == 0) { svar[0] = 0x3F000000u; svar[2] = KCAND; svar[4] = 0u; }
  sw[tid] = 0ull; sw[tid + 512] = 0ull;
  __syncthreads();
  int n = (int)pcnt[16]; if (n > CAP) n = CAP;

  // ---- concat the 16 private segment lists (independent, issue-parallel)
  for (int s = 0; s < NSEG; ++s) {
    const int base = (int)pcnt[s];
    const int cs   = (int)(pcnt[s + 1] - pcnt[s]);
    const uint2* src = cand + ((size_t)(bc * NSEG + s)) * CAPS;
    for (int i = tid; i < cs; i += 512) {
      int d = base + i; if (d < CAP) kv[d] = src[i];
    }
  }
  __syncthreads();

  // ---- radix select: exact key of the 512th largest.
  // keys in (0x3F000000, 0x3F800000) -> top byte fixed 0x3F, scan bytes 2,1,0
  uint32_t K = 0u;
  if (n > KCAND) {
    #pragma unroll
    for (int p = 0; p < 3; p++) {
      const int shift = 16 - 8 * p;
      const uint32_t maskB = (p == 0) ? 0xFF000000u : (p == 1) ? 0xFFFF0000u : 0xFFFFFF00u;
      if (tid < 256) hist[tid] = 0u;
      __syncthreads();
      const uint32_t prefix = svar[0];
      for (int i = tid; i < n; i += 512) {
        uint32_t k = kv[i].x;
        if ((k & maskB) == prefix) atomicAdd(&hist[(k >> shift) & 255u], 1u);
      }
      __syncthreads();
      if (tid < 64) {                       // wave-parallel suffix-scan select
        uint32_t h0 = hist[lane * 4 + 0], h1 = hist[lane * 4 + 1];
        uint32_t h2 = hist[lane * 4 + 2], h3 = hist[lane * 4 + 3];
        uint32_t s3 = h3, s2 = h2 + s3, s1 = h1 + s2, s0 = h0 + s1;
        uint32_t acc = s0;
        #pragma unroll
        for (int o = 1; o < 64; o <<= 1) {
          uint32_t v = __shfl_down(acc, (unsigned)o);
          acc += (lane + o < 64) ? v : 0u;
        }
        uint32_t above = acc - s0;          // sum over bins >= (lane+1)*4
        uint32_t S0 = above + s0, S1 = above + s1, S2 = above + s2, S3 = above + s3, S4 = above;
        uint32_t nd = svar[2];
        if (S0 >= nd && S1 < nd) { svar[0] = prefix | ((uint32_t)(lane * 4 + 0) << shift); svar[2] = nd - S1; }
        if (S1 >= nd && S2 < nd) { svar[0] = prefix | ((uint32_t)(lane * 4 + 1) << shift); svar[2] = nd - S2; }
        if (S2 >= nd && S3 < nd) { svar[0] = prefix | ((uint32_t)(lane * 4 + 2) << shift); svar[2] = nd - S3; }
        if (S3 >= nd && S4 < nd) { svar[0] = prefix | ((uint32_t)(lane * 4 + 3) << shift); svar[2] = nd - S4; }
      }
      __syncthreads();
    }
    K = svar[0];
  }

  // ---- collect keys >= K as packed u64 (ballot-aggregated; ~513 entries)
  const int nr = (n + 511) & ~511;
  for (int i = tid; i < nr; i += 512) {
    bool pred = (i < n) && (kv[i].x >= K);
    unsigned long long m = __ballot(pred ? 1 : 0);
    if (m != 0ull) {
      int leader = (int)__ffsll(m) - 1;
      uint32_t base = 0u;
      if (lane == leader) base = atomicAdd(&svar[4], (uint32_t)__popcll(m));
      base = (uint32_t)__shfl((int)base, leader);
      if (pred) {
        uint32_t q = base + (uint32_t)__popcll(m & ((1ull << lane) - 1ull));
        if (q < 1024u)
          sw[q] = ((unsigned long long)kv[i].x << 32) | (uint32_t)(~kv[i].y);
      }
    }
  }
  __syncthreads();

  // ---- bitonic sort 1024 desc on packed u64 (pads = 0 sink to the end)
  for (int kk = 2; kk <= 1024; kk <<= 1) {
    for (int j = kk >> 1; j > 0; j >>= 1) {
      for (int t = tid; t < 1024; t += 512) {
        int ixj = t ^ j;
        if (ixj > t) {
          unsigned long long wa = sw[t], wb = sw[ixj];
          bool aLess = wa < wb;
          if (((t & kk) == 0) ? aLess : !aLess) { sw[t] = wb; sw[ixj] = wa; }
        }
      }
      __syncthreads();
    }
  }

  // ---- decode boxes for ranks [0, 512) and write to global
  const int limit = (n < KCAND) ? n : KCAND;
  {
    const int r = tid;   // 512 threads == KCAND
    if (r < limit) {
      unsigned long long w = sw[r];
      uint32_t key = (uint32_t)(w >> 32);
      int idx = (int)(~(uint32_t)w);
      float bb[4];
      decode_box(p1, p2, p3, anch, b, idx, bb);
      boxesS[bc * KCAND + r] = make_float4(bb[0], bb[1], bb[2], bb[3]);
      areaS[bc * KCAND + r]  = fmaxf(bb[2] - bb[0], 0.f) * fmaxf(bb[3] - bb[1], 0.f);
      keyS[bc * KCAND + r]   = key;
    } else {
      boxesS[bc * KCAND + r] = make_float4(0.f, 0.f, 0.f, 0.f);
      areaS[bc * KCAND + r]  = 0.f;
      keyS[bc * KCAND + r]   = 0u;
    }
  }
  if (tid == 0) limitG[bc] = limit;
}

// ---------------------------------------------------------------- kernel 3
// one block (256 thr) per (image, class): LDS preload of sorted boxes,
// serial greedy NMS on wave 0 (register kept-list), ballot compaction.
__global__ __launch_bounds__(256) void nms_loop_kernel(
    const float4* __restrict__ boxesS, const float* __restrict__ areaS,
    const uint32_t* __restrict__ keyS, const int* __restrict__ limitG,
    float* __restrict__ selScore, float* __restrict__ selBox,
    int* __restrict__ selRank, int* __restrict__ selCount)
{
  const int bc   = blockIdx.x;
  const int tid  = threadIdx.x;
  const int lane = tid & 63;

  __shared__ float    bxs[512][4];
  __shared__ float    sarea[512];
  __shared__ uint32_t skey[512];
  __shared__ uint32_t pos[512];

  const int limit = limitG[bc];
  for (int r = tid; r < KCAND; r += 256) {
    float4 v = boxesS[bc * KCAND + r];
    bxs[r][0] = v.x; bxs[r][1] = v.y; bxs[r][2] = v.z; bxs[r][3] = v.w;
    sarea[r] = areaS[bc * KCAND + r];
    skey[r]  = keyS[bc * KCAND + r];
  }
  __syncthreads();

  if (tid < 64) {
    float k0x1 = 0.f, k0y1 = 0.f, k0x2 = 0.f, k0y2 = 0.f, k0a = 0.f;
    float k1x1 = 0.f, k1y1 = 0.f, k1x2 = 0.f, k1y2 = 0.f, k1a = 0.f;
    int kept = 0;
    uint32_t keepbits = 0u;
    float c0 = 0.f, c1 = 0.f, c2 = 0.f, c3 = 0.f, ca = 0.f;
    if (limit > 0) {
      float4 cb = *(const float4*)bxs[0];
      c0 = cb.x; c1 = cb.y; c2 = cb.z; c3 = cb.w; ca = sarea[0];
    }
    for (int i = 0; i < limit; i++) {
      int ip = (i + 1 < limit) ? (i + 1) : i;
      float4 nb = *(const float4*)bxs[ip];       // prefetch next (broadcast read)
      float na = sarea[ip];
      bool ov;
      {
        float iw = fmaxf(fminf(c2, k0x2) - fmaxf(c0, k0x1), 0.f);
        float ih = fmaxf(fminf(c3, k0y2) - fmaxf(c1, k0y1), 0.f);
        float inter = iw * ih;
        float uni = fmaxf(ca + k0a - inter, 1e-9f);
        ov = (lane < kept) && (inter / uni > 0.5f);
      }
      {
        float iw = fmaxf(fminf(c2, k1x2) - fmaxf(c0, k1x1), 0.f);
        float ih = fmaxf(fminf(c3, k1y2) - fmaxf(c1, k1y1), 0.f);
        float inter = iw * ih;
        float uni = fmaxf(ca + k1a - inter, 1e-9f);
        ov |= (64 + lane < kept) && (inter / uni > 0.5f);
      }
      if (!__any(ov)) {
        if (lane == (kept & 63)) {
          if (kept < 64) { k0x1 = c0; k0y1 = c1; k0x2 = c2; k0y2 = c3; k0a = ca; }
          else           { k1x1 = c0; k1y1 = c1; k1x2 = c2; k1y2 = c3; k1a = ca; }
        }
        if (lane == (i & 63)) keepbits |= (1u << (i >> 6));
        kept++;
        if (kept >= MAXPC) break;    // cumsum(keep) <= 100 drops anything later
      }
      c0 = nb.x; c1 = nb.y; c2 = nb.z; c3 = nb.w; ca = na;
    }
    // ---- ballot-based compaction positions
    uint32_t total = 0u;
    #pragma unroll
    for (int t = 0; t < 8; t++) {
      unsigned long long m = __ballot((int)((keepbits >> t) & 1u));
      uint32_t pre = total + (uint32_t)__popcll(m & ((1ull << lane) - 1ull));
      pos[t * 64 + lane] = ((keepbits >> t) & 1u) ? pre : 0xFFFFFFFFu;
      total += (uint32_t)__popcll(m);
    }
    if (lane == 0) selCount[bc] = (int)total;   // <= 100 by construction
  }
  __syncthreads();

  // ---- write kept entries (order preserved)
  for (int r = tid; r < KCAND; r += 256) {
    uint32_t p = pos[r];
    if (p < MAXPC) {
      selScore[bc * MAXPC + p] = __uint_as_float(skey[r]);
      selRank[bc * MAXPC + p]  = r;
      float* o = &selBox[(size_t)(bc * MAXPC + p) * 4];
      o[0] = bxs[r][0]; o[1] = bxs[r][1]; o[2] = bxs[r][2]; o[3] = bxs[r][3];
    }
  }
}

// ---------------------------------------------------------------- kernel 4
// per image: merge the two class lists (<=200), exact top-100 by
// (score desc, flat index asc) via rank-by-count, write outputs.
__global__ __launch_bounds__(256) void merge_kernel(
    const float* __restrict__ selScore, const float* __restrict__ selBox,
    const int* __restrict__ selRank, const int* __restrict__ selCount,
    float* __restrict__ out)
{
  const int b   = blockIdx.x;
  const int tid = threadIdx.x;
  __shared__ float    es[200];
  __shared__ uint32_t ek[200];
  __shared__ float    eb[200][4];
  const int c0  = selCount[b * 2 + 0];
  const int c1  = selCount[b * 2 + 1];
  const int tot = c0 + c1;                      // <= 200

  if (tid < tot) {
    int cls  = (tid < c0) ? 0 : 1;
    int slot = (cls == 0) ? tid : (tid - c0);
    int src  = (b * 2 + cls) * MAXPC + slot;
    es[tid] = selScore[src];
    ek[tid] = (uint32_t)(cls * KCAND + selRank[src]);   // flat index in (2,512)
    eb[tid][0] = selBox[(size_t)src * 4 + 0];
    eb[tid][1] = selBox[(size_t)src * 4 + 1];
    eb[tid][2] = selBox[(size_t)src * 4 + 2];
    eb[tid][3] = selBox[(size_t)src * 4 + 3];
  }
  __syncthreads();

  float* outBoxes  = out;
  float* outScores = out + (size_t)BATCH * MAXTOT * 4;
  float* outCls    = outScores + (size_t)BATCH * MAXTOT;
  float* outCnt    = outCls + (size_t)BATCH * MAXTOT;
  const int filled = (tot < MAXTOT) ? tot : MAXTOT;

  if (tid < tot) {
    float    s  = es[tid];
    uint32_t fk = ek[tid];
    int rank = 0;
    for (int j = 0; j < tot; j++)
      rank += (int)((es[j] > s) || (es[j] == s && ek[j] < fk));
    if (rank < MAXTOT) {                       // kept: s > 0.5 > 0 always
      outScores[b * MAXTOT + rank] = s;
      outCls[b * MAXTOT + rank]    = (float)(fk >> 9);
      float* ob = &outBoxes[(size_t)(b * MAXTOT + rank) * 4];
      ob[0] = fminf(fmaxf(eb[tid][0], 0.f), 1.f);
      ob[1] = fminf(fmaxf(eb[tid][1], 0.f), 1.f);
      ob[2] = fminf(fmaxf(eb[tid][2], 0.f), 1.f);
      ob[3] = fminf(fmaxf(eb[tid][3], 0.f), 1.f);
    }
  }
  if (tid >= filled && tid < MAXTOT) {         // zero-fill unused slots
    outScores[b * MAXTOT + tid] = 0.f;
    outCls[b * MAXTOT + tid]    = 0.f;
    float* ob = &outBoxes[(size_t)(b * MAXTOT + tid) * 4];
    ob[0] = 0.f; ob[1] = 0.f; ob[2] = 0.f; ob[3] = 0.f;
  }
  if (tid == 0) outCnt[b] = (float)filled;
}

// ---------------------------------------------------------------- launch
extern "C" void kernel_launch(void* const* d_in, const int* in_sizes, int n_in,
                              void* d_out, int out_size, void* d_ws, size_t ws_size,
                              hipStream_t stream)
{
  const float* p1   = (const float*)d_in[0];
  const float* p2   = (const float*)d_in[1];
  const float* p3   = (const float*)d_in[2];
  const float* anch = (const float*)d_in[3];

  uint8_t* ws = (uint8_t*)d_ws;
  uint32_t* counts = (uint32_t*)ws;                                // 128*16 u32 = 8 KB
  uint2*    cand   = (uint2*)(ws + 16384);                         // 128*16*384*8 = 6 MB
  uint8_t*  wp     = ws + 16384 + (size_t)128 * NSEG * CAPS * 8;
  float4*   boxesS = (float4*)wp;          wp += (size_t)128 * KCAND * 16;
  float*    areaS  = (float*)wp;           wp += (size_t)128 * KCAND * 4;
  uint32_t* keyS   = (uint32_t*)wp;        wp += (size_t)128 * KCAND * 4;
  int*      limitG = (int*)wp;             wp += 512;
  float*    selScore = (float*)wp;         wp += (size_t)BATCH * 2 * MAXPC * 4;
  float*    selBox   = (float*)wp;         wp += (size_t)BATCH * 2 * MAXPC * 16;
  int*      selRank  = (int*)wp;           wp += (size_t)BATCH * 2 * MAXPC * 4;
  int*      selCount = (int*)wp;

  score_filter_kernel<<<BATCH * NSEG, 256, 0, stream>>>(p1, p2, p3, cand, counts);
  select_sort_kernel<<<BATCH * 2, 512, 0, stream>>>(cand, counts, p1, p2, p3, anch,
                                                    boxesS, areaS, keyS, limitG);
  nms_loop_kernel<<<BATCH * 2, 256, 0, stream>>>(boxesS, areaS, keyS, limitG,
                                                 selScore, selBox, selRank, selCount);
  merge_kernel<<<BATCH, 256, 0, stream>>>(selScore, selBox, selRank, selCount,
                                          (float*)d_out);
}

// Round 6
// 86.570 us; speedup vs baseline: 1.1016x; 1.1016x over previous
//
#include <hip/hip_runtime.h>
#include <cstdint>
#include <cstddef>

#define NTOT   22743     // 1083 + 4332 + 17328
#define N1     1083
#define N12    5415
#define BATCH  64
#define KCAND  512
#define NSEG   16        // segments per image
#define SEGLEN 1422      // ceil(NTOT/NSEG)
#define CAPS   384       // per-(b,c,seg) capacity (expected ~114)
#define CAP    4096      // per-(b,c) total candidate capacity in LDS
#define MAXPC  100
#define MAXTOT 100

__device__ __forceinline__ float sigmoidf(float x) { return 1.0f / (1.0f + expf(-x)); }
__device__ __forceinline__ int SK(int j) { return j + (j >> 6); }  // LDS bank skew (stride-64 -> +1)

// ---------------------------------------------------------------- kernel 1
// filter: block = (image b, segment s). Stage the segment's raw preds into
// LDS with coalesced dword copies, compute scores from LDS (stride-7 reads =
// conflict-free), append candidates to LDS lists, write to PRIVATE global slot.
__global__ __launch_bounds__(256) void score_filter_kernel(
    const float* __restrict__ p1, const float* __restrict__ p2,
    const float* __restrict__ p3, uint2* __restrict__ cand,
    uint32_t* __restrict__ counts)
{
  const int blk  = blockIdx.x;
  const int b    = blk >> 4;
  const int s    = blk & 15;
  const int tid  = threadIdx.x;
  const int lane = tid & 63;

  __shared__ float    stage[SEGLEN * 7];   // 39.8 KB
  __shared__ uint2    lst[2][CAPS];        //  6 KB
  __shared__ uint32_t lcnt[2];

  if (tid < 2) lcnt[tid] = 0u;

  const int beg = s * SEGLEN;
  const int end = (beg + SEGLEN < NTOT) ? beg + SEGLEN : NTOT;

  {  // span from p1
    int lo = beg, hi = (end < N1) ? end : N1;
    if (lo < hi) {
      const float* src = p1 + ((size_t)b * 1083 + lo) * 7;
      float* dst = stage + (lo - beg) * 7;
      int cnt = (hi - lo) * 7;
      for (int t = tid; t < cnt; t += 256) dst[t] = src[t];
    }
  }
  {  // span from p2
    int lo = (beg > N1) ? beg : N1, hi = (end < N12) ? end : N12;
    if (lo < hi) {
      const float* src = p2 + ((size_t)b * 4332 + (lo - N1)) * 7;
      float* dst = stage + (lo - beg) * 7;
      int cnt = (hi - lo) * 7;
      for (int t = tid; t < cnt; t += 256) dst[t] = src[t];
    }
  }
  {  // span from p3
    int lo = (beg > N12) ? beg : N12, hi = end;
    if (lo < hi) {
      const float* src = p3 + ((size_t)b * 17328 + (lo - N12)) * 7;
      float* dst = stage + (lo - beg) * 7;
      int cnt = (hi - lo) * 7;
      for (int t = tid; t < cnt; t += 256) dst[t] = src[t];
    }
  }
  __syncthreads();

  #pragma unroll
  for (int k = 0; k < (SEGLEN + 255) / 256; ++k) {
    int i0 = beg + tid + k * 256;
    float s0 = 0.f, s1 = 0.f;
    if (i0 < end) {
      const float* q = &stage[(size_t)(i0 - beg) * 7];
      float q4 = q[4];
      if (q4 > 0.f) {                 // sig(q4)<=0.5 -> product < 0.5 strictly
        float obj = sigmoidf(q4);
        s0 = obj * sigmoidf(q[5]);
        s1 = obj * sigmoidf(q[6]);
      }
    }
    #pragma unroll
    for (int c = 0; c < 2; c++) {
      float sc = (c == 0) ? s0 : s1;
      bool pred = sc > 0.5f;
      unsigned long long m = __ballot(pred ? 1 : 0);
      if (m != 0ull) {
        int leader = (int)__ffsll(m) - 1;
        uint32_t base = 0u;
        if (lane == leader) base = atomicAdd(&lcnt[c], (uint32_t)__popcll(m));
        base = (uint32_t)__shfl((int)base, leader);
        if (pred) {
          uint32_t off = base + (uint32_t)__popcll(m & ((1ull << lane) - 1ull));
          if (off < CAPS) lst[c][off] = make_uint2(__float_as_uint(sc), (uint32_t)i0);
        }
      }
    }
  }
  __syncthreads();

  #pragma unroll
  for (int c = 0; c < 2; c++) {
    uint32_t cnt = lcnt[c]; if (cnt > CAPS) cnt = CAPS;
    uint2* dst = cand + ((size_t)((b * 2 + c) * NSEG + s)) * CAPS;
    for (uint32_t i = tid; i < cnt; i += 256) dst[i] = lst[c][i];
    if (tid == 0) counts[(b * 2 + c) * NSEG + s] = cnt;
  }
}

// box decode for global candidate index i of image b
__device__ void decode_box(const float* __restrict__ p1, const float* __restrict__ p2,
                           const float* __restrict__ p3, const float* __restrict__ anch,
                           int b, int i, float bb[4])
{
  const float* p; int local, g, abase, per;
  if (i < N1)       { p = p1; local = i;       g = 19; abase = 6; per = 1083; }
  else if (i < N12) { p = p2; local = i - N1;  g = 38; abase = 3; per = 4332; }
  else              { p = p3; local = i - N12; g = 76; abase = 0; per = 17328; }
  const float* q = p + ((size_t)b * per + local) * 7;
  int a    = local % 3;
  int cell = local / 3;
  int col  = cell % g;
  int row  = cell / g;
  float aw = anch[(abase + a) * 2 + 0];
  float ah = anch[(abase + a) * 2 + 1];
  float x = (sigmoidf(q[0]) + (float)col) / (float)g;
  float y = (sigmoidf(q[1]) + (float)row) / (float)g;
  float w = expf(q[2]) * aw;
  float h = expf(q[3]) * ah;
  float x1 = x - w * 0.5f;
  float y1 = y - h * 0.5f;
  bb[0] = x1; bb[1] = y1; bb[2] = x1 + w; bb[3] = y1 + h;
}

// ---------------------------------------------------------------- kernel 2
// one block (1024 thr) per (image, class): concat segments, radix-select the
// 512th key, collect >= K packed u64, bitonic sort, decode boxes (skewed SoA),
// chunked mask-precompute NMS (parallel IoU bits + fast serial bitmask pass).
__global__ __launch_bounds__(1024) void nms_kernel(
    const uint2* __restrict__ cand, const uint32_t* __restrict__ counts,
    const float* __restrict__ p1, const float* __restrict__ p2,
    const float* __restrict__ p3, const float* __restrict__ anch,
    float* __restrict__ selScore, float* __restrict__ selBox,
    int* __restrict__ selRank, int* __restrict__ selCount)
{
  const int bc   = blockIdx.x;   // b*2 + c
  const int b    = bc >> 1;
  const int tid  = threadIdx.x;
  const int lane = tid & 63;

  __shared__ uint2              kv[CAP];        // 32 KB
  __shared__ unsigned long long sw[1024];       //  8 KB
  __shared__ float bx1[520], by1[520], bx2[520], by2[520], ar[520]; // 10.2 KB
  __shared__ uint32_t           skey[512];      //  2 KB
  __shared__ unsigned long long msk[128][9];    //  9 KB (row stride 9 = bank skew)
  __shared__ unsigned long long kword[8];
  __shared__ uint32_t           hist[256];
  __shared__ uint32_t           scnt[16], pcnt[17], svar[8];

  // ---- segment counts + prefix
  if (tid < 16) { uint32_t c = counts[bc * NSEG + tid]; scnt[tid] = (c > CAPS) ? CAPS : c; }
  if (tid < 1024) sw[tid] = 0ull;
  __syncthreads();
  if (tid == 0) {
    uint32_t o = 0;
    for (int t = 0; t < 16; ++t) { pcnt[t] = o; o += scnt[t]; }
    pcnt[16] = o;
    svar[0] = 0x3F000000u; svar[2] = KCAND; svar[4] = 0u;
  }
  __syncthreads();
  int n = (int)pcnt[16]; if (n > CAP) n = CAP;

  // ---- concat private segment lists (independent gathers)
  for (int s = 0; s < NSEG; ++s) {
    const int base = (int)pcnt[s];
    const int cs   = (int)scnt[s];
    const uint2* src = cand + ((size_t)(bc * NSEG + s)) * CAPS;
    for (int i = tid; i < cs; i += 1024) {
      int d = base + i; if (d < CAP) kv[d] = src[i];
    }
  }
  __syncthreads();

  // ---- radix select: exact key of the 512th largest (keys share top byte 0x3F)
  uint32_t K = 0u;
  if (n > KCAND) {
    #pragma unroll
    for (int p = 0; p < 3; p++) {
      const int shift = 16 - 8 * p;
      const uint32_t maskB = (p == 0) ? 0xFF000000u : (p == 1) ? 0xFFFF0000u : 0xFFFFFF00u;
      if (tid < 256) hist[tid] = 0u;
      __syncthreads();
      const uint32_t prefix = svar[0];
      for (int i = tid; i < n; i += 1024) {
        uint32_t k = kv[i].x;
        if ((k & maskB) == prefix) atomicAdd(&hist[(k >> shift) & 255u], 1u);
      }
      __syncthreads();
      if (tid < 64) {                       // wave-parallel suffix-scan select
        uint32_t h0 = hist[lane * 4 + 0], h1 = hist[lane * 4 + 1];
        uint32_t h2 = hist[lane * 4 + 2], h3 = hist[lane * 4 + 3];
        uint32_t s3 = h3, s2 = h2 + s3, s1 = h1 + s2, s0 = h0 + s1;
        uint32_t acc = s0;
        #pragma unroll
        for (int o = 1; o < 64; o <<= 1) {
          uint32_t v = __shfl_down(acc, (unsigned)o);
          acc += (lane + o < 64) ? v : 0u;
        }
        uint32_t above = acc - s0;
        uint32_t S0 = above + s0, S1 = above + s1, S2 = above + s2, S3 = above + s3, S4 = above;
        uint32_t nd = svar[2];
        if (S0 >= nd && S1 < nd) { svar[0] = prefix | ((uint32_t)(lane * 4 + 0) << shift); svar[2] = nd - S1; }
        if (S1 >= nd && S2 < nd) { svar[0] = prefix | ((uint32_t)(lane * 4 + 1) << shift); svar[2] = nd - S2; }
        if (S2 >= nd && S3 < nd) { svar[0] = prefix | ((uint32_t)(lane * 4 + 2) << shift); svar[2] = nd - S3; }
        if (S3 >= nd && S4 < nd) { svar[0] = prefix | ((uint32_t)(lane * 4 + 3) << shift); svar[2] = nd - S4; }
      }
      __syncthreads();
    }
    K = svar[0];
  }

  // ---- collect keys >= K packed (key<<32 | ~idx), ballot-aggregated
  const int nr = (n + 1023) & ~1023;
  for (int i = tid; i < nr; i += 1024) {
    bool pred = (i < n) && (kv[i].x >= K);
    unsigned long long m = __ballot(pred ? 1 : 0);
    if (m != 0ull) {
      int leader = (int)__ffsll(m) - 1;
      uint32_t base = 0u;
      if (lane == leader) base = atomicAdd(&svar[4], (uint32_t)__popcll(m));
      base = (uint32_t)__shfl((int)base, leader);
      if (pred) {
        uint32_t q = base + (uint32_t)__popcll(m & ((1ull << lane) - 1ull));
        if (q < 1024u) sw[q] = ((unsigned long long)kv[i].x << 32) | (uint32_t)(~kv[i].y);
      }
    }
  }
  __syncthreads();
  const int mcnt = (int)svar[4];
  const int S = (mcnt <= 512) ? 512 : 1024;

  // ---- bitonic sort S desc on packed u64 (pads = 0 sink to the end)
  for (int kk = 2; kk <= S; kk <<= 1) {
    for (int j = kk >> 1; j > 0; j >>= 1) {
      for (int t = tid; t < S; t += 1024) {
        int ixj = t ^ j;
        if (ixj > t) {
          unsigned long long wa = sw[t], wb = sw[ixj];
          bool aLess = wa < wb;
          if (((t & kk) == 0) ? aLess : !aLess) { sw[t] = wb; sw[ixj] = wa; }
        }
      }
      __syncthreads();
    }
  }

  const int limit = (n < KCAND) ? n : KCAND;

  // ---- decode boxes into bank-skewed SoA
  if (tid < 512) {
    int r = tid;
    if (r < limit) {
      unsigned long long w = sw[r];
      int idx = (int)(~(uint32_t)w);
      float bb[4];
      decode_box(p1, p2, p3, anch, b, idx, bb);
      int p = SK(r);
      bx1[p] = bb[0]; by1[p] = bb[1]; bx2[p] = bb[2]; by2[p] = bb[3];
      ar[p]  = fmaxf(bb[2] - bb[0], 0.f) * fmaxf(bb[3] - bb[1], 0.f);
      skey[r] = (uint32_t)(w >> 32);
    } else {
      int p = SK(r);
      bx1[p] = 0.f; by1[p] = 0.f; bx2[p] = 0.f; by2[p] = 0.f; ar[p] = 0.f;
      skey[r] = 0u;
    }
  }
  __syncthreads();

  // ---- chunked NMS: mask precompute (parallel) + serial bitmask pass (wave 0)
  unsigned long long Kw = 0ull;   // kept bitmap: lane l (<8) owns word l
  int kept = 0;
  bool done = false;

  for (int ch = 0; ch < 4; ++ch) {
    const int base = ch * 128;
    int rows = limit - base; if (rows > 128) rows = 128;

    if (!done && rows > 0) {
      // thread (r = tid>>3, w = tid&7) computes 64-bit mask word w of row r
      const int r = tid >> 3;
      const int w = tid & 7;
      if (r < rows) {
        const int i = base + r;
        if (w <= (i >> 6)) {
          const int ip = SK(i);
          const float x1i = bx1[ip], y1i = by1[ip], x2i = bx2[ip], y2i = by2[ip];
          const float ai = ar[ip];
          unsigned long long mrow = 0ull;
          #pragma unroll 8
          for (int bb = 0; bb < 64; ++bb) {
            int j = (w << 6) + bb;
            int jp = SK(j);
            float iw = fminf(x2i, bx2[jp]) - fmaxf(x1i, bx1[jp]);
            float ih = fminf(y2i, by2[jp]) - fmaxf(y1i, by1[jp]);
            iw = fmaxf(iw, 0.f); ih = fmaxf(ih, 0.f);
            float inter = iw * ih;
            float uni = fmaxf(ai + ar[jp] - inter, 1e-9f);
            bool bit = (inter / uni > 0.5f) && (j < i);
            mrow |= ((unsigned long long)bit) << bb;
          }
          msk[r][w] = mrow;
        } else {
          msk[r][w] = 0ull;
        }
      }
    }
    __syncthreads();

    if (!done && tid < 64) {
      bool stop = false;
      for (int g = 0; g < 16 && !stop; ++g) {
        int r0 = g * 8;
        if (r0 >= rows) break;
        unsigned long long wbuf[8];
        #pragma unroll
        for (int k = 0; k < 8; ++k)
          wbuf[k] = (lane < 8 && (r0 + k) < rows) ? msk[r0 + k][lane] : 0ull;
        #pragma unroll
        for (int k = 0; k < 8; ++k) {
          if (!stop) {
            int r = r0 + k;
            if (r >= rows) { stop = true; }
            else {
              int i = base + r;
              bool ov = (Kw & wbuf[k]) != 0ull;
              if (!__any(ov)) {
                if (lane == (i >> 6)) Kw |= 1ull << (i & 63);
                if (++kept >= MAXPC) stop = true;
              }
            }
          }
        }
      }
      if (lane == 0) svar[5] = (kept >= MAXPC || (base + ((rows > 0) ? rows : 0)) >= limit) ? 1u : 0u;
    }
    __syncthreads();
    done = (svar[5] != 0u);
  }

  if (tid < 8) kword[tid] = 0ull;
  __syncthreads();
  if (tid < 8) kword[tid] = Kw;      // only wave-0 lanes hold real Kw; others wrote 0 first
  __syncthreads();
  // NOTE: lanes 8..63 of wave 0 also reach "tid<8"? no — tid<8 is lanes 0..7 of wave 0 only.

  // ---- write kept entries (prefix over kword)
  if (tid < 512) {
    int r = tid;
    int wr = r >> 6;
    unsigned long long kw = kword[wr];
    if ((kw >> (r & 63)) & 1ull) {
      uint32_t p = 0;
      for (int w = 0; w < wr; ++w) p += (uint32_t)__popcll(kword[w]);
      p += (uint32_t)__popcll(kw & ((1ull << (r & 63)) - 1ull));
      selScore[bc * MAXPC + p] = __uint_as_float(skey[r]);
      selRank[bc * MAXPC + p]  = r;
      int rp = SK(r);
      float* o = &selBox[(size_t)(bc * MAXPC + p) * 4];
      o[0] = bx1[rp]; o[1] = by1[rp]; o[2] = bx2[rp]; o[3] = by2[rp];
    }
  }
  if (tid == 0) {
    uint32_t tot = 0;
    for (int w = 0; w < 8; ++w) tot += (uint32_t)__popcll(kword[w]);
    selCount[bc] = (int)tot;
  }
}

// ---------------------------------------------------------------- kernel 3
// per image: merge the two class lists (<=200), exact top-100 by
// (score desc, flat index asc) via rank-by-count, write outputs.
__global__ __launch_bounds__(256) void merge_kernel(
    const float* __restrict__ selScore, const float* __restrict__ selBox,
    const int* __restrict__ selRank, const int* __restrict__ selCount,
    float* __restrict__ out)
{
  const int b   = blockIdx.x;
  const int tid = threadIdx.x;
  __shared__ float    es[200];
  __shared__ uint32_t ek[200];
  __shared__ float    eb[200][4];
  const int c0  = selCount[b * 2 + 0];
  const int c1  = selCount[b * 2 + 1];
  const int tot = c0 + c1;                      // <= 200

  if (tid < tot) {
    int cls  = (tid < c0) ? 0 : 1;
    int slot = (cls == 0) ? tid : (tid - c0);
    int src  = (b * 2 + cls) * MAXPC + slot;
    es[tid] = selScore[src];
    ek[tid] = (uint32_t)(cls * KCAND + selRank[src]);   // flat index in (2,512)
    eb[tid][0] = selBox[(size_t)src * 4 + 0];
    eb[tid][1] = selBox[(size_t)src * 4 + 1];
    eb[tid][2] = selBox[(size_t)src * 4 + 2];
    eb[tid][3] = selBox[(size_t)src * 4 + 3];
  }
  __syncthreads();

  float* outBoxes  = out;
  float* outScores = out + (size_t)BATCH * MAXTOT * 4;
  float* outCls    = outScores + (size_t)BATCH * MAXTOT;
  float* outCnt    = outCls + (size_t)BATCH * MAXTOT;
  const int filled = (tot < MAXTOT) ? tot : MAXTOT;

  if (tid < tot) {
    float    s  = es[tid];
    uint32_t fk = ek[tid];
    int rank = 0;
    for (int j = 0; j < tot; j++)
      rank += (int)((es[j] > s) || (es[j] == s && ek[j] < fk));
    if (rank < MAXTOT) {                       // kept: s > 0.5 > 0 always
      outScores[b * MAXTOT + rank] = s;
      outCls[b * MAXTOT + rank]    = (float)(fk >> 9);
      float* ob = &outBoxes[(size_t)(b * MAXTOT + rank) * 4];
      ob[0] = fminf(fmaxf(eb[tid][0], 0.f), 1.f);
      ob[1] = fminf(fmaxf(eb[tid][1], 0.f), 1.f);
      ob[2] = fminf(fmaxf(eb[tid][2], 0.f), 1.f);
      ob[3] = fminf(fmaxf(eb[tid][3], 0.f), 1.f);
    }
  }
  if (tid >= filled && tid < MAXTOT) {         // zero-fill unused slots
    outScores[b * MAXTOT + tid] = 0.f;
    outCls[b * MAXTOT + tid]    = 0.f;
    float* ob = &outBoxes[(size_t)(b * MAXTOT + tid) * 4];
    ob[0] = 0.f; ob[1] = 0.f; ob[2] = 0.f; ob[3] = 0.f;
  }
  if (tid == 0) outCnt[b] = (float)filled;
}

// ---------------------------------------------------------------- launch
extern "C" void kernel_launch(void* const* d_in, const int* in_sizes, int n_in,
                              void* d_out, int out_size, void* d_ws, size_t ws_size,
                              hipStream_t stream)
{
  const float* p1   = (const float*)d_in[0];
  const float* p2   = (const float*)d_in[1];
  const float* p3   = (const float*)d_in[2];
  const float* anch = (const float*)d_in[3];

  uint8_t* ws = (uint8_t*)d_ws;
  uint32_t* counts = (uint32_t*)ws;                                // 2048 u32
  uint2*    cand   = (uint2*)(ws + 16384);                         // 128*16*384*8 = 6 MB
  uint8_t*  wp     = ws + 16384 + (size_t)128 * NSEG * CAPS * 8;
  float*    selScore = (float*)wp;         wp += (size_t)BATCH * 2 * MAXPC * 4;
  float*    selBox   = (float*)wp;         wp += (size_t)BATCH * 2 * MAXPC * 16;
  int*      selRank  = (int*)wp;           wp += (size_t)BATCH * 2 * MAXPC * 4;
  int*      selCount = (int*)wp;

  score_filter_kernel<<<BATCH * NSEG, 256, 0, stream>>>(p1, p2, p3, cand, counts);
  nms_kernel<<<BATCH * 2, 1024, 0, stream>>>(cand, counts, p1, p2, p3, anch,
                                             selScore, selBox, selRank, selCount);
  merge_kernel<<<BATCH, 256, 0, stream>>>(selScore, selBox, selRank, selCount,
                                          (float*)d_out);
}

// Round 7
// 81.752 us; speedup vs baseline: 1.1665x; 1.0589x over previous
//
#include <hip/hip_runtime.h>
#include <cstdint>
#include <cstddef>

#define NTOT   22743     // 1083 + 4332 + 17328
#define N1     1083
#define N12    5415
#define BATCH  64
#define KCAND  512
#define NSEG   16        // segments per image
#define SEGLEN 1422      // ceil(NTOT/NSEG)
#define CAPS   384       // per-(b,c,seg) capacity (expected ~114)
#define CAP    4096      // per-(b,c) total candidate capacity in LDS
#define MAXPC  100
#define MAXTOT 100

__device__ __forceinline__ float sigmoidf(float x) { return 1.0f / (1.0f + expf(-x)); }
__device__ __forceinline__ int SK(int j) { return j + (j >> 6); }  // LDS bank skew

// coalesced global->LDS span copy, float4 body
__device__ __forceinline__ void copy_span(const float* __restrict__ src,
                                          float* __restrict__ dst, int cnt, int tid)
{
  int head = (int)((16 - ((size_t)src & 15)) & 15) >> 2;   // dwords to 16B-align src
  if (head > cnt) head = cnt;
  for (int t = tid; t < head; t += 256) dst[t] = src[t];
  int body = (cnt - head) >> 2;
  const float4* s4 = (const float4*)(src + head);
  float* d0 = dst + head;
  for (int t = tid; t < body; t += 256) {
    float4 v = s4[t];
    d0[t * 4 + 0] = v.x; d0[t * 4 + 1] = v.y; d0[t * 4 + 2] = v.z; d0[t * 4 + 3] = v.w;
  }
  for (int t = head + body * 4 + tid; t < cnt; t += 256) dst[t] = src[t];
}

// ---------------------------------------------------------------- kernel 1
// filter: block = (image b, segment s). Stage segment preds into LDS
// (float4-coalesced), score from LDS, append candidates to LDS lists,
// write to PRIVATE global slot. No global atomics.
__global__ __launch_bounds__(256) void score_filter_kernel(
    const float* __restrict__ p1, const float* __restrict__ p2,
    const float* __restrict__ p3, uint2* __restrict__ cand,
    uint32_t* __restrict__ counts)
{
  const int blk  = blockIdx.x;
  const int b    = blk >> 4;
  const int s    = blk & 15;
  const int tid  = threadIdx.x;
  const int lane = tid & 63;

  __shared__ float    stage[SEGLEN * 7];   // 39.8 KB
  __shared__ uint2    lst[2][CAPS];        //  6 KB
  __shared__ uint32_t lcnt[2];

  if (tid < 2) lcnt[tid] = 0u;

  const int beg = s * SEGLEN;
  const int end = (beg + SEGLEN < NTOT) ? beg + SEGLEN : NTOT;

  {  // span from p1
    int lo = beg, hi = (end < N1) ? end : N1;
    if (lo < hi)
      copy_span(p1 + ((size_t)b * 1083 + lo) * 7, stage + (lo - beg) * 7, (hi - lo) * 7, tid);
  }
  {  // span from p2
    int lo = (beg > N1) ? beg : N1, hi = (end < N12) ? end : N12;
    if (lo < hi)
      copy_span(p2 + ((size_t)b * 4332 + (lo - N1)) * 7, stage + (lo - beg) * 7, (hi - lo) * 7, tid);
  }
  {  // span from p3
    int lo = (beg > N12) ? beg : N12, hi = end;
    if (lo < hi)
      copy_span(p3 + ((size_t)b * 17328 + (lo - N12)) * 7, stage + (lo - beg) * 7, (hi - lo) * 7, tid);
  }
  __syncthreads();

  #pragma unroll
  for (int k = 0; k < (SEGLEN + 255) / 256; ++k) {
    int i0 = beg + tid + k * 256;
    float s0 = 0.f, s1 = 0.f;
    if (i0 < end) {
      const float* q = &stage[(size_t)(i0 - beg) * 7];
      float q4 = q[4];
      if (q4 > 0.f) {                 // sig(q4)<=0.5 -> product < 0.5 strictly
        float obj = sigmoidf(q4);
        s0 = obj * sigmoidf(q[5]);
        s1 = obj * sigmoidf(q[6]);
      }
    }
    #pragma unroll
    for (int c = 0; c < 2; c++) {
      float sc = (c == 0) ? s0 : s1;
      bool pred = sc > 0.5f;
      unsigned long long m = __ballot(pred ? 1 : 0);
      if (m != 0ull) {
        int leader = (int)__ffsll(m) - 1;
        uint32_t base = 0u;
        if (lane == leader) base = atomicAdd(&lcnt[c], (uint32_t)__popcll(m));
        base = (uint32_t)__shfl((int)base, leader);
        if (pred) {
          uint32_t off = base + (uint32_t)__popcll(m & ((1ull << lane) - 1ull));
          if (off < CAPS) lst[c][off] = make_uint2(__float_as_uint(sc), (uint32_t)i0);
        }
      }
    }
  }
  __syncthreads();

  #pragma unroll
  for (int c = 0; c < 2; c++) {
    uint32_t cnt = lcnt[c]; if (cnt > CAPS) cnt = CAPS;
    uint2* dst = cand + ((size_t)((b * 2 + c) * NSEG + s)) * CAPS;
    for (uint32_t i = tid; i < cnt; i += 256) dst[i] = lst[c][i];
    if (tid == 0) counts[(b * 2 + c) * NSEG + s] = cnt;
  }
}

// box decode for global candidate index i of image b
__device__ void decode_box(const float* __restrict__ p1, const float* __restrict__ p2,
                           const float* __restrict__ p3, const float* __restrict__ anch,
                           int b, int i, float bb[4])
{
  const float* p; int local, g, abase, per;
  if (i < N1)       { p = p1; local = i;       g = 19; abase = 6; per = 1083; }
  else if (i < N12) { p = p2; local = i - N1;  g = 38; abase = 3; per = 4332; }
  else              { p = p3; local = i - N12; g = 76; abase = 0; per = 17328; }
  const float* q = p + ((size_t)b * per + local) * 7;
  int a    = local % 3;
  int cell = local / 3;
  int col  = cell % g;
  int row  = cell / g;
  float aw = anch[(abase + a) * 2 + 0];
  float ah = anch[(abase + a) * 2 + 1];
  float x = (sigmoidf(q[0]) + (float)col) / (float)g;
  float y = (sigmoidf(q[1]) + (float)row) / (float)g;
  float w = expf(q[2]) * aw;
  float h = expf(q[3]) * ah;
  float x1 = x - w * 0.5f;
  float y1 = y - h * 0.5f;
  bb[0] = x1; bb[1] = y1; bb[2] = x1 + w; bb[3] = y1 + h;
}

// ---------------------------------------------------------------- kernel 2
// one block (1024 thr) per (image, class): flat concat (packed u64), radix-
// select the 512th key (7 barriers), ballot-collect >= K, rank-by-count
// (1 barrier) with direct scatter-decode, chunked mask-precompute NMS.
__global__ __launch_bounds__(1024) void nms_kernel(
    const uint2* __restrict__ cand, const uint32_t* __restrict__ counts,
    const float* __restrict__ p1, const float* __restrict__ p2,
    const float* __restrict__ p3, const float* __restrict__ anch,
    float* __restrict__ selScore, float* __restrict__ selBox,
    int* __restrict__ selRank, int* __restrict__ selCount)
{
  const int bc   = blockIdx.x;   // b*2 + c
  const int b    = bc >> 1;
  const int tid  = threadIdx.x;
  const int lane = tid & 63;

  __shared__ unsigned long long kvw[CAP];       // 32 KB packed (key<<32 | ~idx)
  __shared__ unsigned long long sw[1024];       //  8 KB collected top candidates
  __shared__ float bx1[520], by1[520], bx2[520], by2[520], ar[520]; // 10.2 KB
  __shared__ uint32_t           skey[512];      //  2 KB
  __shared__ unsigned long long msk[128][9];    //  9 KB (row stride 9 = skew)
  __shared__ unsigned long long kword[8];
  __shared__ uint32_t           hist3[768];     //  3 KB (one hist per radix pass)
  __shared__ uint32_t           scnt[16], pcnt[17], svar[8];

  // ---- init
  if (tid < 16) { uint32_t c = counts[bc * NSEG + tid]; scnt[tid] = (c > CAPS) ? CAPS : c; }
  if (tid < 768) hist3[tid] = 0u;
  if (tid == 0) { svar[0] = 0x3F000000u; svar[2] = KCAND; svar[4] = 0u; svar[5] = 0u; }
  if (tid < 512) {
    skey[tid] = 0u; int p = SK(tid);
    bx1[p] = 0.f; by1[p] = 0.f; bx2[p] = 0.f; by2[p] = 0.f; ar[p] = 0.f;
  }
  __syncthreads();
  if (tid == 0) { uint32_t o = 0; for (int t = 0; t < 16; ++t) { pcnt[t] = o; o += scnt[t]; } pcnt[16] = o; }
  __syncthreads();
  const int n = ((int)pcnt[16] < CAP) ? (int)pcnt[16] : CAP;

  // ---- flat concat: per-element segment lookup, pack u64
  for (int i = tid; i < n; i += 1024) {
    int s = 0;
    #pragma unroll
    for (int t = 1; t < 16; ++t) s += (int)(i >= (int)pcnt[t]);
    uint2 e = cand[(size_t)(bc * NSEG + s) * CAPS + (i - (int)pcnt[s])];
    kvw[i] = ((unsigned long long)e.x << 32) | (uint32_t)(~e.y);
  }
  __syncthreads();

  const uint32_t* kv2 = (const uint32_t*)kvw;   // hi word at 2*i+1 = key

  // ---- radix select: exact key of the 512th largest (top byte fixed 0x3F)
  uint32_t K = 0u;
  if (n > KCAND) {
    #pragma unroll
    for (int p = 0; p < 3; p++) {
      const int shift = 16 - 8 * p;
      const uint32_t maskB = (p == 0) ? 0xFF000000u : (p == 1) ? 0xFFFF0000u : 0xFFFFFF00u;
      uint32_t* hist = &hist3[p * 256];
      const uint32_t prefix = svar[0];
      for (int i = tid; i < n; i += 1024) {
        uint32_t k = kv2[2 * i + 1];
        if ((k & maskB) == prefix) atomicAdd(&hist[(k >> shift) & 255u], 1u);
      }
      __syncthreads();
      if (tid < 64) {                       // wave-parallel suffix-scan select
        uint32_t h0 = hist[lane * 4 + 0], h1 = hist[lane * 4 + 1];
        uint32_t h2 = hist[lane * 4 + 2], h3 = hist[lane * 4 + 3];
        uint32_t s3 = h3, s2 = h2 + s3, s1 = h1 + s2, s0 = h0 + s1;
        uint32_t acc = s0;
        #pragma unroll
        for (int o = 1; o < 64; o <<= 1) {
          uint32_t v = __shfl_down(acc, (unsigned)o);
          acc += (lane + o < 64) ? v : 0u;
        }
        uint32_t above = acc - s0;
        uint32_t S0 = above + s0, S1 = above + s1, S2 = above + s2, S3 = above + s3, S4 = above;
        uint32_t nd = svar[2];
        if (S0 >= nd && S1 < nd) { svar[0] = prefix | ((uint32_t)(lane * 4 + 0) << shift); svar[2] = nd - S1; }
        if (S1 >= nd && S2 < nd) { svar[0] = prefix | ((uint32_t)(lane * 4 + 1) << shift); svar[2] = nd - S2; }
        if (S2 >= nd && S3 < nd) { svar[0] = prefix | ((uint32_t)(lane * 4 + 2) << shift); svar[2] = nd - S3; }
        if (S3 >= nd && S4 < nd) { svar[0] = prefix | ((uint32_t)(lane * 4 + 3) << shift); svar[2] = nd - S4; }
      }
      __syncthreads();
    }
    K = svar[0];
  }

  // ---- collect keys >= K (ballot-aggregated; ~513 entries)
  const int nr = (n + 1023) & ~1023;
  for (int i = tid; i < nr; i += 1024) {
    bool pred = (i < n) && (kv2[2 * i + 1] >= K);
    unsigned long long m = __ballot(pred ? 1 : 0);
    if (m != 0ull) {
      int leader = (int)__ffsll(m) - 1;
      uint32_t base = 0u;
      if (lane == leader) base = atomicAdd(&svar[4], (uint32_t)__popcll(m));
      base = (uint32_t)__shfl((int)base, leader);
      if (pred) {
        uint32_t q = base + (uint32_t)__popcll(m & ((1ull << lane) - 1ull));
        if (q < 1024u) sw[q] = kvw[i];
      }
    }
  }
  __syncthreads();
  const int mc = ((int)svar[4] < 1024) ? (int)svar[4] : 1024;
  const int limit = (n < KCAND) ? n : KCAND;

  // ---- rank-by-count (order-independent) + scatter decode to SoA[rank]
  if (tid < mc) {
    unsigned long long e = sw[tid];
    int rank = 0;
    #pragma unroll 4
    for (int j = 0; j < mc; ++j) rank += (int)(sw[j] > e);
    if (rank < KCAND) {
      int idx = (int)(~(uint32_t)e);
      float bb[4];
      decode_box(p1, p2, p3, anch, b, idx, bb);
      int p = SK(rank);
      bx1[p] = bb[0]; by1[p] = bb[1]; bx2[p] = bb[2]; by2[p] = bb[3];
      ar[p]  = fmaxf(bb[2] - bb[0], 0.f) * fmaxf(bb[3] - bb[1], 0.f);
      skey[rank] = (uint32_t)(e >> 32);
    }
  }
  __syncthreads();

  // ---- chunked NMS: parallel mask words + serial bitmask pass (wave 0)
  unsigned long long Kw = 0ull;   // kept bitmap: lane l (<8) owns word l
  int kept = 0;
  bool done = false;

  for (int ch = 0; ch < 4; ++ch) {
    const int base = ch * 128;
    int rows = limit - base; if (rows > 128) rows = 128;

    if (!done && rows > 0) {
      const int r = tid >> 3;
      const int w = tid & 7;
      if (r < rows) {
        const int i = base + r;
        if (w <= (i >> 6)) {
          const int ip = SK(i);
          const float x1i = bx1[ip], y1i = by1[ip], x2i = bx2[ip], y2i = by2[ip];
          const float ai = ar[ip];
          unsigned long long mrow = 0ull;
          #pragma unroll 8
          for (int bb = 0; bb < 64; ++bb) {
            int j = (w << 6) + bb;
            int jp = SK(j);
            float iw = fminf(x2i, bx2[jp]) - fmaxf(x1i, bx1[jp]);
            float ih = fminf(y2i, by2[jp]) - fmaxf(y1i, by1[jp]);
            iw = fmaxf(iw, 0.f); ih = fmaxf(ih, 0.f);
            float inter = iw * ih;
            float uni = fmaxf(ai + ar[jp] - inter, 1e-9f);
            bool bit = (inter / uni > 0.5f) && (j < i);
            mrow |= ((unsigned long long)bit) << bb;
          }
          msk[r][w] = mrow;
        } else {
          msk[r][w] = 0ull;
        }
      }
    }
    __syncthreads();

    if (!done && rows > 0 && tid < 64) {
      bool stop = false;
      for (int g = 0; g < 16 && !stop; ++g) {
        int r0 = g * 8;
        if (r0 >= rows) break;
        unsigned long long wbuf[8];
        #pragma unroll
        for (int k2 = 0; k2 < 8; ++k2)
          wbuf[k2] = (lane < 8 && (r0 + k2) < rows) ? msk[r0 + k2][lane] : 0ull;
        #pragma unroll
        for (int k2 = 0; k2 < 8; ++k2) {
          if (!stop) {
            int r = r0 + k2;
            if (r >= rows) { stop = true; }
            else {
              int i = base + r;
              bool ov = (Kw & wbuf[k2]) != 0ull;
              if (!__any(ov)) {
                if (lane == (i >> 6)) Kw |= 1ull << (i & 63);
                if (++kept >= MAXPC) stop = true;
              }
            }
          }
        }
      }
      if (lane == 0) svar[5] = (kept >= MAXPC || (base + rows) >= limit) ? 1u : 0u;
    }
    __syncthreads();
    done = done || (svar[5] != 0u);
  }

  if (tid < 8) kword[tid] = Kw;    // wave-0 lanes 0..7 hold the kept words
  __syncthreads();

  // ---- write kept entries (prefix over kword)
  if (tid < 512) {
    int r = tid;
    int wr = r >> 6;
    unsigned long long kw = kword[wr];
    if ((kw >> (r & 63)) & 1ull) {
      uint32_t p = 0;
      for (int w = 0; w < wr; ++w) p += (uint32_t)__popcll(kword[w]);
      p += (uint32_t)__popcll(kw & ((1ull << (r & 63)) - 1ull));
      selScore[bc * MAXPC + p] = __uint_as_float(skey[r]);
      selRank[bc * MAXPC + p]  = r;
      int rp = SK(r);
      float* o = &selBox[(size_t)(bc * MAXPC + p) * 4];
      o[0] = bx1[rp]; o[1] = by1[rp]; o[2] = bx2[rp]; o[3] = by2[rp];
    }
  }
  if (tid == 0) {
    uint32_t tot = 0;
    for (int w = 0; w < 8; ++w) tot += (uint32_t)__popcll(kword[w]);
    selCount[bc] = (int)tot;
  }
}

// ---------------------------------------------------------------- kernel 3
// per image: merge the two class lists (<=200), exact top-100 by
// (score desc, flat index asc) via rank-by-count, write outputs.
__global__ __launch_bounds__(256) void merge_kernel(
    const float* __restrict__ selScore, const float* __restrict__ selBox,
    const int* __restrict__ selRank, const int* __restrict__ selCount,
    float* __restrict__ out)
{
  const int b   = blockIdx.x;
  const int tid = threadIdx.x;
  __shared__ float    es[200];
  __shared__ uint32_t ek[200];
  __shared__ float    eb[200][4];
  const int c0  = selCount[b * 2 + 0];
  const int c1  = selCount[b * 2 + 1];
  const int tot = c0 + c1;                      // <= 200

  if (tid < tot) {
    int cls  = (tid < c0) ? 0 : 1;
    int slot = (cls == 0) ? tid : (tid - c0);
    int src  = (b * 2 + cls) * MAXPC + slot;
    es[tid] = selScore[src];
    ek[tid] = (uint32_t)(cls * KCAND + selRank[src]);   // flat index in (2,512)
    eb[tid][0] = selBox[(size_t)src * 4 + 0];
    eb[tid][1] = selBox[(size_t)src * 4 + 1];
    eb[tid][2] = selBox[(size_t)src * 4 + 2];
    eb[tid][3] = selBox[(size_t)src * 4 + 3];
  }
  __syncthreads();

  float* outBoxes  = out;
  float* outScores = out + (size_t)BATCH * MAXTOT * 4;
  float* outCls    = outScores + (size_t)BATCH * MAXTOT;
  float* outCnt    = outCls + (size_t)BATCH * MAXTOT;
  const int filled = (tot < MAXTOT) ? tot : MAXTOT;

  if (tid < tot) {
    float    s  = es[tid];
    uint32_t fk = ek[tid];
    int rank = 0;
    for (int j = 0; j < tot; j++)
      rank += (int)((es[j] > s) || (es[j] == s && ek[j] < fk));
    if (rank < MAXTOT) {                       // kept: s > 0.5 > 0 always
      outScores[b * MAXTOT + rank] = s;
      outCls[b * MAXTOT + rank]    = (float)(fk >> 9);
      float* ob = &outBoxes[(size_t)(b * MAXTOT + rank) * 4];
      ob[0] = fminf(fmaxf(eb[tid][0], 0.f), 1.f);
      ob[1] = fminf(fmaxf(eb[tid][1], 0.f), 1.f);
      ob[2] = fminf(fmaxf(eb[tid][2], 0.f), 1.f);
      ob[3] = fminf(fmaxf(eb[tid][3], 0.f), 1.f);
    }
  }
  if (tid >= filled && tid < MAXTOT) {         // zero-fill unused slots
    outScores[b * MAXTOT + tid] = 0.f;
    outCls[b * MAXTOT + tid]    = 0.f;
    float* ob = &outBoxes[(size_t)(b * MAXTOT + tid) * 4];
    ob[0] = 0.f; ob[1] = 0.f; ob[2] = 0.f; ob[3] = 0.f;
  }
  if (tid == 0) outCnt[b] = (float)filled;
}

// ---------------------------------------------------------------- launch
extern "C" void kernel_launch(void* const* d_in, const int* in_sizes, int n_in,
                              void* d_out, int out_size, void* d_ws, size_t ws_size,
                              hipStream_t stream)
{
  const float* p1   = (const float*)d_in[0];
  const float* p2   = (const float*)d_in[1];
  const float* p3   = (const float*)d_in[2];
  const float* anch = (const float*)d_in[3];

  uint8_t* ws = (uint8_t*)d_ws;
  uint32_t* counts = (uint32_t*)ws;                                // 2048 u32
  uint2*    cand   = (uint2*)(ws + 16384);                         // 128*16*384*8 = 6 MB
  uint8_t*  wp     = ws + 16384 + (size_t)128 * NSEG * CAPS * 8;
  float*    selScore = (float*)wp;         wp += (size_t)BATCH * 2 * MAXPC * 4;
  float*    selBox   = (float*)wp;         wp += (size_t)BATCH * 2 * MAXPC * 16;
  int*      selRank  = (int*)wp;           wp += (size_t)BATCH * 2 * MAXPC * 4;
  int*      selCount = (int*)wp;

  score_filter_kernel<<<BATCH * NSEG, 256, 0, stream>>>(p1, p2, p3, cand, counts);
  nms_kernel<<<BATCH * 2, 1024, 0, stream>>>(cand, counts, p1, p2, p3, anch,
                                             selScore, selBox, selRank, selCount);
  merge_kernel<<<BATCH, 256, 0, stream>>>(selScore, selBox, selRank, selCount,
                                          (float*)d_out);
}

// Round 8
// 62.585 us; speedup vs baseline: 1.5237x; 1.3063x over previous
//
#include <hip/hip_runtime.h>
#include <cstdint>
#include <cstddef>

#define NTOT   22743     // 1083 + 4332 + 17328
#define N1     1083
#define N12    5415
#define BATCH  64
#define KCAND  512
#define NSEG   16        // segments per image
#define SEGLEN 1422      // ceil(NTOT/NSEG)
#define CAPS   384       // per-(b,c,seg) capacity (expected ~114)
#define CAP    4096      // per-(b,c) total candidate capacity (4 regs/thread)
#define MAXPC  100
#define MAXTOT 100

__device__ __forceinline__ float sigmoidf(float x) { return 1.0f / (1.0f + expf(-x)); }
__device__ __forceinline__ int SK4(int j) { return j + ((j >> 6) << 2); }  // float4-friendly skew

// ---------------------------------------------------------------- kernel 1
// filter: block = (image b, segment s). Direct global reads (only q4,q5,q6),
// ballot-aggregated LDS append, write to PRIVATE global slot. No staging.
__global__ __launch_bounds__(256) void score_filter_kernel(
    const float* __restrict__ p1, const float* __restrict__ p2,
    const float* __restrict__ p3, uint2* __restrict__ cand,
    uint32_t* __restrict__ counts)
{
  const int blk  = blockIdx.x;
  const int b    = blk >> 4;
  const int s    = blk & 15;
  const int tid  = threadIdx.x;
  const int lane = tid & 63;

  __shared__ uint2    lst[2][CAPS];
  __shared__ uint32_t lcnt[2];

  if (tid < 2) lcnt[tid] = 0u;
  __syncthreads();

  const int beg = s * SEGLEN;
  const int end = (beg + SEGLEN < NTOT) ? beg + SEGLEN : NTOT;

  for (int i0 = beg + tid; i0 < beg + SEGLEN; i0 += 256) {   // uniform trip count
    float s0 = 0.f, s1 = 0.f;
    if (i0 < end) {
      const float* p; int local, per;
      if (i0 < N1)       { p = p1; local = i0;        per = 1083; }
      else if (i0 < N12) { p = p2; local = i0 - N1;   per = 4332; }
      else               { p = p3; local = i0 - N12;  per = 17328; }
      const float* q = p + ((size_t)b * per + local) * 7;
      float q4 = q[4];
      if (q4 > 0.f) {                 // sig(q4)<=0.5 -> product < 0.5 strictly
        float obj = sigmoidf(q4);
        s0 = obj * sigmoidf(q[5]);
        s1 = obj * sigmoidf(q[6]);
      }
    }
    #pragma unroll
    for (int c = 0; c < 2; c++) {
      float sc = (c == 0) ? s0 : s1;
      bool pred = sc > 0.5f;
      unsigned long long m = __ballot(pred ? 1 : 0);
      if (m != 0ull) {
        int leader = (int)__ffsll(m) - 1;
        uint32_t base = 0u;
        if (lane == leader) base = atomicAdd(&lcnt[c], (uint32_t)__popcll(m));
        base = (uint32_t)__shfl((int)base, leader);
        if (pred) {
          uint32_t off = base + (uint32_t)__popcll(m & ((1ull << lane) - 1ull));
          if (off < CAPS) lst[c][off] = make_uint2(__float_as_uint(sc), (uint32_t)i0);
        }
      }
    }
  }
  __syncthreads();

  #pragma unroll
  for (int c = 0; c < 2; c++) {
    uint32_t cnt = lcnt[c]; if (cnt > CAPS) cnt = CAPS;
    uint2* dst = cand + ((size_t)((b * 2 + c) * NSEG + s)) * CAPS;
    for (uint32_t i = tid; i < cnt; i += 256) dst[i] = lst[c][i];
    if (tid == 0) counts[(b * 2 + c) * NSEG + s] = cnt;
  }
}

// box decode for global candidate index i of image b
__device__ void decode_box(const float* __restrict__ p1, const float* __restrict__ p2,
                           const float* __restrict__ p3, const float* __restrict__ anch,
                           int b, int i, float bb[4])
{
  const float* p; int local, g, abase, per;
  if (i < N1)       { p = p1; local = i;       g = 19; abase = 6; per = 1083; }
  else if (i < N12) { p = p2; local = i - N1;  g = 38; abase = 3; per = 4332; }
  else              { p = p3; local = i - N12; g = 76; abase = 0; per = 17328; }
  const float* q = p + ((size_t)b * per + local) * 7;
  int a    = local % 3;
  int cell = local / 3;
  int col  = cell % g;
  int row  = cell / g;
  float aw = anch[(abase + a) * 2 + 0];
  float ah = anch[(abase + a) * 2 + 1];
  float x = (sigmoidf(q[0]) + (float)col) / (float)g;
  float y = (sigmoidf(q[1]) + (float)row) / (float)g;
  float w = expf(q[2]) * aw;
  float h = expf(q[3]) * ah;
  float x1 = x - w * 0.5f;
  float y1 = y - h * 0.5f;
  bb[0] = x1; bb[1] = y1; bb[2] = x1 + w; bb[3] = y1 + h;
}

// ---------------------------------------------------------------- kernel 2
// one block (1024 thr) per (image, class). Candidates live in REGISTERS
// (<=4 packed u64/thread). Radix-select 512th key (reg scans), ballot-collect
// >= K to LDS, rank-by-count with b128 paired broadcast stream (4 waves x 2
// elems/lane), scatter-decode to SK4 SoA, broadcast-float4 mask NMS.
__global__ __launch_bounds__(1024) void nms_kernel(
    const uint2* __restrict__ cand, const uint32_t* __restrict__ counts,
    const float* __restrict__ p1, const float* __restrict__ p2,
    const float* __restrict__ p3, const float* __restrict__ anch,
    float* __restrict__ selScore, float* __restrict__ selBox,
    int* __restrict__ selRank, int* __restrict__ selCount)
{
  const int bc   = blockIdx.x;   // b*2 + c
  const int b    = bc >> 1;
  const int tid  = threadIdx.x;
  const int lane = tid & 63;

  __shared__ __attribute__((aligned(16))) unsigned long long sw[1024];   // 8 KB
  __shared__ __attribute__((aligned(16))) float bx1[544];
  __shared__ __attribute__((aligned(16))) float by1[544];
  __shared__ __attribute__((aligned(16))) float bx2[544];
  __shared__ __attribute__((aligned(16))) float by2[544];
  __shared__ __attribute__((aligned(16))) float ar[544];                 // 10.6 KB
  __shared__ uint32_t           skey[512];      // 2 KB
  __shared__ unsigned long long msk[128][9];    // 9 KB (row stride 9 = skew)
  __shared__ unsigned long long kword[8];
  __shared__ uint32_t           hist3[768];     // 3 KB, one hist per radix pass
  __shared__ uint32_t           svar[8];

  // ---- init LDS
  if (tid < 768) hist3[tid] = 0u;
  sw[tid] = 0ull;
  if (tid == 0) { svar[0] = 0x3F000000u; svar[2] = KCAND; svar[4] = 0u; svar[5] = 0u; }
  if (tid < 512) {
    skey[tid] = 0u; int p = SK4(tid);
    bx1[p] = 0.f; by1[p] = 0.f; bx2[p] = 0.f; by2[p] = 0.f; ar[p] = 0.f;
  }

  // ---- uniform prefix of segment counts (global loads, no LDS)
  uint32_t pc[17];
  pc[0] = 0;
  #pragma unroll
  for (int t = 0; t < 16; ++t) {
    uint32_t c = counts[bc * NSEG + t];
    if (c > CAPS) c = CAPS;
    pc[t + 1] = pc[t] + c;
  }
  const int n = ((int)pc[16] < CAP) ? (int)pc[16] : CAP;

  // ---- load my candidates into registers (packed: key<<32 | ~idx)
  unsigned long long v0 = 0ull, v1 = 0ull, v2 = 0ull, v3 = 0ull;
  auto loadc = [&](int i) -> unsigned long long {
    if (i >= n) return 0ull;
    uint32_t ps = 0; int s = 0;
    #pragma unroll
    for (int t = 1; t < 16; ++t) {
      bool ge = (uint32_t)i >= pc[t];
      s += (int)ge; ps = ge ? pc[t] : ps;
    }
    uint2 e = cand[(size_t)(bc * NSEG + s) * CAPS + (i - (int)ps)];
    return ((unsigned long long)e.x << 32) | (uint32_t)(~e.y);
  };
  v0 = loadc(tid); v1 = loadc(tid + 1024); v2 = loadc(tid + 2048); v3 = loadc(tid + 3072);
  __syncthreads();

  // ---- radix select: exact key of the 512th largest (top byte fixed 0x3F)
  uint32_t K = 0u;
  if (n > KCAND) {
    #pragma unroll
    for (int p = 0; p < 3; p++) {
      const int shift = 16 - 8 * p;
      const uint32_t maskB = (p == 0) ? 0xFF000000u : (p == 1) ? 0xFFFF0000u : 0xFFFFFF00u;
      uint32_t* hist = &hist3[p * 256];
      const uint32_t prefix = svar[0];
      {
        uint32_t k;
        k = (uint32_t)(v0 >> 32); if (v0 && (k & maskB) == prefix) atomicAdd(&hist[(k >> shift) & 255u], 1u);
        k = (uint32_t)(v1 >> 32); if (v1 && (k & maskB) == prefix) atomicAdd(&hist[(k >> shift) & 255u], 1u);
        k = (uint32_t)(v2 >> 32); if (v2 && (k & maskB) == prefix) atomicAdd(&hist[(k >> shift) & 255u], 1u);
        k = (uint32_t)(v3 >> 32); if (v3 && (k & maskB) == prefix) atomicAdd(&hist[(k >> shift) & 255u], 1u);
      }
      __syncthreads();
      if (tid < 64) {                       // wave-parallel suffix-scan select
        uint32_t h0 = hist[lane * 4 + 0], h1 = hist[lane * 4 + 1];
        uint32_t h2 = hist[lane * 4 + 2], h3 = hist[lane * 4 + 3];
        uint32_t s3 = h3, s2 = h2 + s3, s1 = h1 + s2, s0 = h0 + s1;
        uint32_t acc = s0;
        #pragma unroll
        for (int o = 1; o < 64; o <<= 1) {
          uint32_t v = __shfl_down(acc, (unsigned)o);
          acc += (lane + o < 64) ? v : 0u;
        }
        uint32_t above = acc - s0;
        uint32_t S0 = above + s0, S1 = above + s1, S2 = above + s2, S3 = above + s3, S4 = above;
        uint32_t nd = svar[2];
        if (S0 >= nd && S1 < nd) { svar[0] = prefix | ((uint32_t)(lane * 4 + 0) << shift); svar[2] = nd - S1; }
        if (S1 >= nd && S2 < nd) { svar[0] = prefix | ((uint32_t)(lane * 4 + 1) << shift); svar[2] = nd - S2; }
        if (S2 >= nd && S3 < nd) { svar[0] = prefix | ((uint32_t)(lane * 4 + 2) << shift); svar[2] = nd - S3; }
        if (S3 >= nd && S4 < nd) { svar[0] = prefix | ((uint32_t)(lane * 4 + 3) << shift); svar[2] = nd - S4; }
      }
      __syncthreads();
    }
    K = svar[0];
  }

  // ---- collect keys >= K to sw (ballot-aggregated, 4 rounds, from regs)
  {
    auto coll = [&](unsigned long long vv) {
      bool pred = (vv != 0ull) && ((uint32_t)(vv >> 32) >= K);
      unsigned long long m = __ballot(pred ? 1 : 0);
      if (m != 0ull) {
        int leader = (int)__ffsll(m) - 1;
        uint32_t base = 0u;
        if (lane == leader) base = atomicAdd(&svar[4], (uint32_t)__popcll(m));
        base = (uint32_t)__shfl((int)base, leader);
        if (pred) {
          uint32_t q = base + (uint32_t)__popcll(m & ((1ull << lane) - 1ull));
          if (q < 1024u) sw[q] = vv;
        }
      }
    };
    coll(v0); coll(v1); coll(v2); coll(v3);
  }
  __syncthreads();
  const int mc = ((int)svar[4] < 1024) ? (int)svar[4] : 1024;
  const int limit = (n < KCAND) ? n : KCAND;

  // ---- rank-by-count: 4 waves, 2 (or 4) elems/lane, b128 paired stream
  if (tid < 256) {
    const ulonglong2* sw2 = (const ulonglong2*)sw;
    const int np = (mc + 1) >> 1;              // sw[mc]==0 pads odd mc
    unsigned long long E0 = sw[tid], E1 = sw[tid + 256];
    int R0 = 0, R1 = 0;
    auto scat = [&](unsigned long long E, int R) {
      if (E != 0ull && R < KCAND) {
        int idx = (int)(~(uint32_t)E);
        float bb[4];
        decode_box(p1, p2, p3, anch, b, idx, bb);
        int p = SK4(R);
        bx1[p] = bb[0]; by1[p] = bb[1]; bx2[p] = bb[2]; by2[p] = bb[3];
        ar[p]  = fmaxf(bb[2] - bb[0], 0.f) * fmaxf(bb[3] - bb[1], 0.f);
        skey[R] = (uint32_t)(E >> 32);
      }
    };
    if (mc <= 512) {
      for (int j = 0; j < np; ++j) {
        ulonglong2 v = sw2[j];
        R0 += (int)(v.x > E0) + (int)(v.y > E0);
        R1 += (int)(v.x > E1) + (int)(v.y > E1);
      }
      scat(E0, R0); scat(E1, R1);
    } else {
      unsigned long long E2 = sw[tid + 512], E3 = sw[tid + 768];
      int R2 = 0, R3 = 0;
      for (int j = 0; j < np; ++j) {
        ulonglong2 v = sw2[j];
        R0 += (int)(v.x > E0) + (int)(v.y > E0);
        R1 += (int)(v.x > E1) + (int)(v.y > E1);
        R2 += (int)(v.x > E2) + (int)(v.y > E2);
        R3 += (int)(v.x > E3) + (int)(v.y > E3);
      }
      scat(E0, R0); scat(E1, R1); scat(E2, R2); scat(E3, R3);
    }
  }
  __syncthreads();

  // ---- chunked NMS: broadcast-float4 mask words + serial bitmask pass
  unsigned long long Kw = 0ull;   // kept bitmap: wave-0 lane l (<8) owns word l
  int kept = 0;
  const int r = tid & 127;        // row within chunk
  const int w = tid >> 7;         // mask word (wave-uniform!)

  for (int ch = 0; ch < 4; ++ch) {
    const int base = ch * 128;
    int rows = limit - base; if (rows > 128) rows = 128;

    if (r < rows) {
      const int i = base + r;
      if (w <= (i >> 6)) {
        const int ip = SK4(i);
        const float x1i = bx1[ip], y1i = by1[ip], x2i = bx2[ip], y2i = by2[ip];
        const float ai = ar[ip];
        unsigned long long mrow = 0ull;
        #pragma unroll
        for (int m4 = 0; m4 < 16; ++m4) {
          const int j0 = (w << 6) + (m4 << 2);
          const int a  = j0 + (w << 2);          // SK4(j0), j0>>6 == w
          float4 X1 = *(const float4*)&bx1[a];
          float4 Y1 = *(const float4*)&by1[a];
          float4 X2 = *(const float4*)&bx2[a];
          float4 Y2 = *(const float4*)&by2[a];
          float4 AR = *(const float4*)&ar[a];
          #define IOU_BIT(JX1,JY1,JX2,JY2,JAR,J)                              \
            { float iw = fminf(x2i,(JX2)) - fmaxf(x1i,(JX1));                 \
              float ih = fminf(y2i,(JY2)) - fmaxf(y1i,(JY1));                 \
              iw = fmaxf(iw,0.f); ih = fmaxf(ih,0.f);                        \
              float inter = iw*ih;                                            \
              float uni = fmaxf(ai + (JAR) - inter, 1e-9f);                   \
              if ((inter/uni > 0.5f) && ((J) < i))                            \
                mrow |= 1ull << ((J) & 63); }
          IOU_BIT(X1.x, Y1.x, X2.x, Y2.x, AR.x, j0 + 0)
          IOU_BIT(X1.y, Y1.y, X2.y, Y2.y, AR.y, j0 + 1)
          IOU_BIT(X1.z, Y1.z, X2.z, Y2.z, AR.z, j0 + 2)
          IOU_BIT(X1.w, Y1.w, X2.w, Y2.w, AR.w, j0 + 3)
          #undef IOU_BIT
        }
        msk[r][w] = mrow;
      } else {
        msk[r][w] = 0ull;
      }
    }
    __syncthreads();

    if (tid < 64) {
      bool stop = false;
      for (int g = 0; g < 16 && !stop; ++g) {
        int r0 = g * 8;
        if (r0 >= rows) break;
        unsigned long long wbuf[8];
        #pragma unroll
        for (int k2 = 0; k2 < 8; ++k2)
          wbuf[k2] = (lane < 8 && (r0 + k2) < rows) ? msk[r0 + k2][lane] : 0ull;
        #pragma unroll
        for (int k2 = 0; k2 < 8; ++k2) {
          if (!stop) {
            int rr = r0 + k2;
            if (rr >= rows) { stop = true; }
            else {
              int i = base + rr;
              bool ov = (Kw & wbuf[k2]) != 0ull;
              if (!__any(ov)) {
                if (lane == (i >> 6)) Kw |= 1ull << (i & 63);
                if (++kept >= MAXPC) stop = true;
              }
            }
          }
        }
      }
      if (lane == 0) svar[5] = (kept >= MAXPC || (base + (rows > 0 ? rows : 0)) >= limit) ? 1u : 0u;
    }
    __syncthreads();
    if (svar[5] != 0u) break;     // block-uniform break
  }

  if (tid < 8) kword[tid] = Kw;   // wave-0 lanes 0..7 hold the kept words
  __syncthreads();

  // ---- write kept entries (prefix over kword)
  if (tid < 512) {
    int rr = tid;
    int wr = rr >> 6;
    unsigned long long kw = kword[wr];
    if ((kw >> (rr & 63)) & 1ull) {
      uint32_t p = 0;
      for (int ww = 0; ww < wr; ++ww) p += (uint32_t)__popcll(kword[ww]);
      p += (uint32_t)__popcll(kw & ((1ull << (rr & 63)) - 1ull));
      selScore[bc * MAXPC + p] = __uint_as_float(skey[rr]);
      selRank[bc * MAXPC + p]  = rr;
      int rp = SK4(rr);
      float* o = &selBox[(size_t)(bc * MAXPC + p) * 4];
      o[0] = bx1[rp]; o[1] = by1[rp]; o[2] = bx2[rp]; o[3] = by2[rp];
    }
  }
  if (tid == 0) {
    uint32_t tot = 0;
    for (int ww = 0; ww < 8; ++ww) tot += (uint32_t)__popcll(kword[ww]);
    selCount[bc] = (int)tot;
  }
}

// ---------------------------------------------------------------- kernel 3
// per image: merge the two class lists (<=200), exact top-100 by
// (score desc, flat index asc) via rank-by-count, write outputs.
__global__ __launch_bounds__(256) void merge_kernel(
    const float* __restrict__ selScore, const float* __restrict__ selBox,
    const int* __restrict__ selRank, const int* __restrict__ selCount,
    float* __restrict__ out)
{
  const int b   = blockIdx.x;
  const int tid = threadIdx.x;
  __shared__ float    es[200];
  __shared__ uint32_t ek[200];
  __shared__ float    eb[200][4];
  const int c0  = selCount[b * 2 + 0];
  const int c1  = selCount[b * 2 + 1];
  const int tot = c0 + c1;                      // <= 200

  if (tid < tot) {
    int cls  = (tid < c0) ? 0 : 1;
    int slot = (cls == 0) ? tid : (tid - c0);
    int src  = (b * 2 + cls) * MAXPC + slot;
    es[tid] = selScore[src];
    ek[tid] = (uint32_t)(cls * KCAND + selRank[src]);   // flat index in (2,512)
    eb[tid][0] = selBox[(size_t)src * 4 + 0];
    eb[tid][1] = selBox[(size_t)src * 4 + 1];
    eb[tid][2] = selBox[(size_t)src * 4 + 2];
    eb[tid][3] = selBox[(size_t)src * 4 + 3];
  }
  __syncthreads();

  float* outBoxes  = out;
  float* outScores = out + (size_t)BATCH * MAXTOT * 4;
  float* outCls    = outScores + (size_t)BATCH * MAXTOT;
  float* outCnt    = outCls + (size_t)BATCH * MAXTOT;
  const int filled = (tot < MAXTOT) ? tot : MAXTOT;

  if (tid < tot) {
    float    s  = es[tid];
    uint32_t fk = ek[tid];
    int rank = 0;
    for (int j = 0; j < tot; j++)
      rank += (int)((es[j] > s) || (es[j] == s && ek[j] < fk));
    if (rank < MAXTOT) {                       // kept: s > 0.5 > 0 always
      outScores[b * MAXTOT + rank] = s;
      outCls[b * MAXTOT + rank]    = (float)(fk >> 9);
      float* ob = &outBoxes[(size_t)(b * MAXTOT + rank) * 4];
      ob[0] = fminf(fmaxf(eb[tid][0], 0.f), 1.f);
      ob[1] = fminf(fmaxf(eb[tid][1], 0.f), 1.f);
      ob[2] = fminf(fmaxf(eb[tid][2], 0.f), 1.f);
      ob[3] = fminf(fmaxf(eb[tid][3], 0.f), 1.f);
    }
  }
  if (tid >= filled && tid < MAXTOT) {         // zero-fill unused slots
    outScores[b * MAXTOT + tid] = 0.f;
    outCls[b * MAXTOT + tid]    = 0.f;
    float* ob = &outBoxes[(size_t)(b * MAXTOT + tid) * 4];
    ob[0] = 0.f; ob[1] = 0.f; ob[2] = 0.f; ob[3] = 0.f;
  }
  if (tid == 0) outCnt[b] = (float)filled;
}

// ---------------------------------------------------------------- launch
extern "C" void kernel_launch(void* const* d_in, const int* in_sizes, int n_in,
                              void* d_out, int out_size, void* d_ws, size_t ws_size,
                              hipStream_t stream)
{
  const float* p1   = (const float*)d_in[0];
  const float* p2   = (const float*)d_in[1];
  const float* p3   = (const float*)d_in[2];
  const float* anch = (const float*)d_in[3];

  uint8_t* ws = (uint8_t*)d_ws;
  uint32_t* counts = (uint32_t*)ws;                                // 2048 u32
  uint2*    cand   = (uint2*)(ws + 16384);                         // 128*16*384*8 = 6 MB
  uint8_t*  wp     = ws + 16384 + (size_t)128 * NSEG * CAPS * 8;
  float*    selScore = (float*)wp;         wp += (size_t)BATCH * 2 * MAXPC * 4;
  float*    selBox   = (float*)wp;         wp += (size_t)BATCH * 2 * MAXPC * 16;
  int*      selRank  = (int*)wp;           wp += (size_t)BATCH * 2 * MAXPC * 4;
  int*      selCount = (int*)wp;

  score_filter_kernel<<<BATCH * NSEG, 256, 0, stream>>>(p1, p2, p3, cand, counts);
  nms_kernel<<<BATCH * 2, 1024, 0, stream>>>(cand, counts, p1, p2, p3, anch,
                                             selScore, selBox, selRank, selCount);
  merge_kernel<<<BATCH, 256, 0, stream>>>(selScore, selBox, selRank, selCount,
                                          (float*)d_out);
}